// Round 2
// baseline (460.102 us; speedup 1.0000x reference)
//
#include <hip/hip_runtime.h>

#define CDIV(a,b) (((a)+(b)-1)/(b))

typedef __bf16 bf16_t;
typedef unsigned char u8;
typedef bf16_t bf16x8 __attribute__((ext_vector_type(8)));
typedef float floatx4 __attribute__((ext_vector_type(4)));
typedef float floatx2 __attribute__((ext_vector_type(2)));

// sigma2: storage position p -> original feature index (within 256).
__device__ __forceinline__ int sigma2(int p) {
    int tile = p >> 7, hh = (p >> 6) & 1, m = (p >> 2) & 15, c = p & 3;
    return tile * 128 + (hh * 4 + c) * 16 + m;
}

// pack 4 fp32 -> 4 OCP e4m3 bytes
__device__ __forceinline__ unsigned pack4_fp8(float a, float b, float c, float d) {
    int v = __builtin_amdgcn_cvt_pk_fp8_f32(a, b, 0, false);   // bytes [1:0]
    v = __builtin_amdgcn_cvt_pk_fp8_f32(c, d, v, true);        // bytes [3:2]
    return (unsigned)v;
}

template<bool HI>
__device__ __forceinline__ floatx2 cvtf8(unsigned v) {
    return __builtin_amdgcn_cvt_pk_f32_fp8(v, HI);   // HI is constexpr
}

// DPP butterfly add: x + lane-permuted(x).  CTRL: 0xB1 = quad_perm xor1,
// 0x4E = quad_perm xor2.  Pure VALU — no lgkmcnt wait like ds_swizzle.
template<int CTRL>
__device__ __forceinline__ float dpp_add(float x) {
    int v = __builtin_amdgcn_update_dpp(0, __float_as_int(x), CTRL, 0xf, 0xf, true);
    return x + __int_as_float(v);
}

// ---------------------------------------------------------------------------
// K1: per-original-edge degree count (single atomic; edge-attr sum for the
// self-loop fill moved to k_selfloop, which is atomic-free).
__global__ void k_deg(const int* __restrict__ ei, int* __restrict__ deg, int E) {
    int e = blockIdx.x * 256 + threadIdx.x;
    if (e >= E) return;
    atomicAdd(&deg[ei[E + e]], 1);
}

// K3: parallel exclusive scan of (deg[i]+1) -> off[0..n], 3 phases.
__global__ void k_scanA(const int* __restrict__ deg, int* __restrict__ part, int n) {
    __shared__ int sh[256];
    int t = threadIdx.x;
    int i = blockIdx.x * 256 + t;
    int v = (i < n) ? deg[i] + 1 : 0;
    sh[t] = v;
    __syncthreads();
    for (int d = 128; d > 0; d >>= 1) { if (t < d) sh[t] += sh[t + d]; __syncthreads(); }
    if (t == 0) part[blockIdx.x] = sh[0];
}
__global__ void k_scanB(int* __restrict__ part, int nb) {
    __shared__ int sh[256];
    int t = threadIdx.x;
    int v = (t < nb) ? part[t] : 0;
    sh[t] = v;
    __syncthreads();
    for (int d = 1; d < 256; d <<= 1) {
        int u = (t >= d) ? sh[t - d] : 0;
        __syncthreads();
        sh[t] += u;
        __syncthreads();
    }
    if (t < nb) part[t] = sh[t] - v;   // exclusive
}
__global__ void k_scanC(const int* __restrict__ deg, const int* __restrict__ part,
                        int* __restrict__ off, int n) {
    __shared__ int sh[256];
    int t = threadIdx.x;
    int i = blockIdx.x * 256 + t;
    int v = (i < n) ? deg[i] + 1 : 0;
    sh[t] = v;
    __syncthreads();
    for (int d = 1; d < 256; d <<= 1) {
        int u = (t >= d) ? sh[t - d] : 0;
        __syncthreads();
        sh[t] += u;
        __syncthreads();
    }
    int excl = part[blockIdx.x] + sh[t] - v;
    if (i < n) off[i] = excl;
    if (i == n - 1) off[n] = excl + v;
}

// K4: CSR fill of ORIGINAL edges only; originals occupy [off[d], off[d+1]-1),
// the last slot of each segment is reserved for the self-loop (k_selfloop).
__global__ void k_fill(const int* __restrict__ ei, const float* __restrict__ ea,
                       const int* __restrict__ off, int* __restrict__ cursor,
                       int2* __restrict__ csr, int E) {
    int e = blockIdx.x * 256 + threadIdx.x;
    if (e >= E) return;
    int s = ei[e], d = ei[E + e];
    int pos = off[d] + atomicAdd(&cursor[d], 1);
    csr[pos] = make_int2(s, __float_as_int(ea[e]));
}

// K4b: per-node self-loop entry (atomic-free).  Sums the segment's original
// edge attrs -> loop_attr = sum / max(deg,1); writes csr[off[i+1]-1].
__global__ void k_selfloop(const int* __restrict__ off, int2* __restrict__ csr, int n) {
    int i = blockIdx.x * 256 + threadIdx.x;
    if (i >= n) return;
    int p0 = off[i], p1 = off[i + 1] - 1;   // originals in [p0, p1)
    float s = 0.0f;
    for (int p = p0; p < p1; ++p) s += __int_as_float(csr[p].y);
    float la = s / fmaxf((float)(p1 - p0), 1.0f);
    csr[p1] = make_int2(i, __float_as_int(la));
}

// K5c: combined weight transpose+cast Wl,Wr[K,256] fp32 -> Wt[512,K] bf16.
__global__ void k_wcast2(const float* __restrict__ Wl, const float* __restrict__ Wr,
                         const float* __restrict__ bl, const float* __restrict__ br,
                         bf16_t* __restrict__ Wt, float* __restrict__ bias2,
                         int K, int kshift, int permK,
                         const float* __restrict__ we, const float* __restrict__ att,
                         const float* __restrict__ cb,
                         float* __restrict__ wep, float* __restrict__ attp,
                         float* __restrict__ cbp) {
    int idx = blockIdx.x * 256 + threadIdx.x;
    if (idx < 512) bias2[idx] = (idx < 256) ? bl[idx] : br[idx - 256];
    if (idx < 256) {
        int sg = sigma2(idx);
        wep[idx] = we[sg]; attp[idx] = att[sg]; cbp[idx] = cb[sg];
    }
    if (idx >= 512 * K) return;
    int nn = idx >> kshift, k = idx & (K - 1);
    int ks = permK ? sigma2(k) : k;
    float v = (nn < 256) ? Wl[ks * 256 + nn] : Wr[ks * 256 + (nn - 256)];
    Wt[idx] = (bf16_t)v;
}

// K6a: layer-1 GEMM with fused encoder.  grid.y=2 splits the 4 col-tiles.
__global__ __launch_bounds__(256) void k_gemm1_fused(
        const float* __restrict__ x, const float* __restrict__ encw,
        const float* __restrict__ encb, const bf16_t* __restrict__ Wt,
        const float* __restrict__ bias2, u8* __restrict__ XL,
        u8* __restrict__ XR, int nrows) {
    __shared__ bf16_t As[128 * 32];
    __shared__ bf16_t Bs[128 * 32];
    int tid = threadIdx.x;
    int w = tid >> 6, lane = tid & 63;
    int quad = lane >> 4, m = lane & 15;
    int row0 = blockIdx.x * 128;
    int ct0 = blockIdx.y * 2;
    bf16x8 afr[2][2];
    floatx4 acc[2][8];

    for (int ctile = ct0; ctile < ct0 + 2; ++ctile) {
        int n0 = ctile * 128;
#pragma unroll
        for (int rt = 0; rt < 2; ++rt)
#pragma unroll
            for (int ct = 0; ct < 8; ++ct)
                acc[rt][ct] = (floatx4){0.f, 0.f, 0.f, 0.f};
        for (int k0c = 0; k0c < 2; ++k0c) {
            __syncthreads();
            if (ctile == ct0) {
#pragma unroll
                for (int i = 0; i < 2; ++i) {  // stage A: fused encoder
                    int c = tid + i * 256;
                    int r = c >> 2, kc = c & 3;
                    int sw = (kc + (r >> 1)) & 3;
                    int gr = row0 + r; if (gr >= nrows) gr = nrows - 1;
                    float4 xv = ((const float4*)x)[gr];
                    bf16x8 v;
#pragma unroll
                    for (int kk = 0; kk < 8; ++kk) {
                        int k = k0c * 32 + kc * 8 + kk;
                        float s = encb[k];
                        s = fmaf(xv.x, encw[k], s);
                        s = fmaf(xv.y, encw[64 + k], s);
                        s = fmaf(xv.z, encw[128 + k], s);
                        s = fmaf(xv.w, encw[192 + k], s);
                        v[kk] = (bf16_t)fmaxf(s, 0.0f);
                    }
                    *(bf16x8*)&As[r * 32 + sw * 8] = v;
                }
            }
#pragma unroll
            for (int i = 0; i < 2; ++i) {      // stage B for this col-tile
                int c = tid + i * 256;
                int r = c >> 2, kc = c & 3;
                int sw = (kc + (r >> 1)) & 3;
                bf16x8 v = *(const bf16x8*)&Wt[(size_t)(n0 + r) * 64 + k0c * 32 + kc * 8];
                *(bf16x8*)&Bs[r * 32 + sw * 8] = v;
            }
            __syncthreads();
            if (ctile == ct0) {
#pragma unroll
                for (int rt = 0; rt < 2; ++rt) {
                    int ar = w * 32 + rt * 16 + m;
                    afr[k0c][rt] = *(bf16x8*)&As[ar * 32 + (((quad + (ar >> 1)) & 3) * 8)];
                }
            }
            bf16x8 bfr[8];
#pragma unroll
            for (int ct = 0; ct < 8; ++ct) {
                int br = ct * 16 + m;
                bfr[ct] = *(bf16x8*)&Bs[br * 32 + (((quad + (br >> 1)) & 3) * 8)];
            }
#pragma unroll
            for (int ct = 0; ct < 8; ++ct) {
                acc[0][ct] = __builtin_amdgcn_mfma_f32_16x16x32_bf16(afr[k0c][0], bfr[ct], acc[0][ct], 0, 0, 0);
                acc[1][ct] = __builtin_amdgcn_mfma_f32_16x16x32_bf16(afr[k0c][1], bfr[ct], acc[1][ct], 0, 0, 0);
            }
        }
        int tile = ctile & 1;
        u8* dst = (ctile < 2) ? XL : XR;
        float bv[8];
#pragma unroll
        for (int ct = 0; ct < 8; ++ct) bv[ct] = bias2[n0 + ct * 16 + m];
#pragma unroll
        for (int rt = 0; rt < 2; ++rt) {
#pragma unroll
            for (int i = 0; i < 4; ++i) {
                int row = row0 + w * 32 + rt * 16 + quad * 4 + i;
                if (row < nrows) {
                    unsigned w0 = pack4_fp8(acc[rt][0][i] + bv[0], acc[rt][1][i] + bv[1],
                                            acc[rt][2][i] + bv[2], acc[rt][3][i] + bv[3]);
                    unsigned w1 = pack4_fp8(acc[rt][4][i] + bv[4], acc[rt][5][i] + bv[5],
                                            acc[rt][6][i] + bv[6], acc[rt][7][i] + bv[7]);
                    *(unsigned*)&dst[(size_t)row * 256 + tile * 128 + m * 4] = w0;
                    *(unsigned*)&dst[(size_t)row * 256 + tile * 128 + 64 + m * 4] = w1;
                }
            }
        }
    }
}

// K6b: layer-2 GEMM (K=256), grid.y=2 col-tile split; A staged once/block.
__global__ __launch_bounds__(256) void k_gemm2(
        const bf16_t* __restrict__ Hb, const bf16_t* __restrict__ Wt,
        const float* __restrict__ bias2, u8* __restrict__ XL,
        u8* __restrict__ XR, int nrows) {
    const int K = 256;
    __shared__ bf16_t As[128 * 32];
    __shared__ bf16_t Bs[128 * 32];
    int tid = threadIdx.x;
    int w = tid >> 6, lane = tid & 63;
    int quad = lane >> 4, m = lane & 15;
    int row0 = blockIdx.x * 128;
    int ct0 = blockIdx.y * 2;
    bf16x8 afr[8][2];
    floatx4 acc[2][8];

    for (int ctile = ct0; ctile < ct0 + 2; ++ctile) {
        int n0 = ctile * 128;
#pragma unroll
        for (int rt = 0; rt < 2; ++rt)
#pragma unroll
            for (int ct = 0; ct < 8; ++ct)
                acc[rt][ct] = (floatx4){0.f, 0.f, 0.f, 0.f};
        for (int k0c = 0; k0c < 8; ++k0c) {
            __syncthreads();
            if (ctile == ct0) {
#pragma unroll
                for (int i = 0; i < 2; ++i) {
                    int c = tid + i * 256;
                    int r = c >> 2, kc = c & 3;
                    int sw = (kc + (r >> 1)) & 3;
                    int gr = row0 + r; if (gr >= nrows) gr = nrows - 1;
                    bf16x8 v = *(const bf16x8*)&Hb[(size_t)gr * K + k0c * 32 + kc * 8];
                    *(bf16x8*)&As[r * 32 + sw * 8] = v;
                }
            }
#pragma unroll
            for (int i = 0; i < 2; ++i) {
                int c = tid + i * 256;
                int r = c >> 2, kc = c & 3;
                int sw = (kc + (r >> 1)) & 3;
                bf16x8 v = *(const bf16x8*)&Wt[(size_t)(n0 + r) * K + k0c * 32 + kc * 8];
                *(bf16x8*)&Bs[r * 32 + sw * 8] = v;
            }
            __syncthreads();
            if (ctile == ct0) {
#pragma unroll
                for (int rt = 0; rt < 2; ++rt) {
                    int ar = w * 32 + rt * 16 + m;
                    afr[k0c][rt] = *(bf16x8*)&As[ar * 32 + (((quad + (ar >> 1)) & 3) * 8)];
                }
            }
            bf16x8 bfr[8];
#pragma unroll
            for (int ct = 0; ct < 8; ++ct) {
                int br = ct * 16 + m;
                bfr[ct] = *(bf16x8*)&Bs[br * 32 + (((quad + (br >> 1)) & 3) * 8)];
            }
#pragma unroll
            for (int ct = 0; ct < 8; ++ct) {
                acc[0][ct] = __builtin_amdgcn_mfma_f32_16x16x32_bf16(afr[k0c][0], bfr[ct], acc[0][ct], 0, 0, 0);
                acc[1][ct] = __builtin_amdgcn_mfma_f32_16x16x32_bf16(afr[k0c][1], bfr[ct], acc[1][ct], 0, 0, 0);
            }
        }
        int tile = ctile & 1;
        u8* dst = (ctile < 2) ? XL : XR;
        float bv[8];
#pragma unroll
        for (int ct = 0; ct < 8; ++ct) bv[ct] = bias2[n0 + ct * 16 + m];
#pragma unroll
        for (int rt = 0; rt < 2; ++rt) {
#pragma unroll
            for (int i = 0; i < 4; ++i) {
                int row = row0 + w * 32 + rt * 16 + quad * 4 + i;
                if (row < nrows) {
                    unsigned w0 = pack4_fp8(acc[rt][0][i] + bv[0], acc[rt][1][i] + bv[1],
                                            acc[rt][2][i] + bv[2], acc[rt][3][i] + bv[3]);
                    unsigned w1 = pack4_fp8(acc[rt][4][i] + bv[4], acc[rt][5][i] + bv[5],
                                            acc[rt][6][i] + bv[6], acc[rt][7][i] + bv[7]);
                    *(unsigned*)&dst[(size_t)row * 256 + tile * 128 + m * 4] = w0;
                    *(unsigned*)&dst[(size_t)row * 256 + tile * 128 + 64 + m * 4] = w1;
                }
            }
        }
    }
}

// K7: fused GATv2 conv, fp8 XL/XR (256B/edge), sigma2 layout.  One wave per
// dst node; FOUR 16-lane groups each own one edge (lane covers 16 features,
// dwordx4 gather = 16B/lane sweet spot).  Head = storage_pos>>6, so each
// aligned lane-quad covers exactly one head -> 2-level DPP reduce.
// R2: (a) 4 edges/wave-instr (was 2) — tail (reduce/exp/fetch/loop) cost per
// edge halves, loads & bpermutes per edge halve; (b) leaky-relu eliminated
// algebraically: att·lrelu(t) = av6·t + (2/3)·av6·|t| with av6=0.6·log2e·att
// (|t| is a free VOP3 abs modifier on v_fma) — kills 8 pk_mul + 16 v_max per
// iteration; (c) 32-bit gather offsets (saddr+voffset form).
// Plain (cached) csr loads + Hb stores: R15 showed non-temporal hints
// REGRESS conv (FETCH +3.7MB).  NOTE: no __launch_bounds__ — R7: higher
// occupancy thrashes L2.  NOTE: pool fusion reverted — R9: same-graph
// atomics serialize.
__global__ void k_conv(
                       const u8* __restrict__ XL, const u8* __restrict__ XR,
                       const float* __restrict__ wep, const float* __restrict__ attp,
                       const int2* __restrict__ csr,
                       const int* __restrict__ off, const float* __restrict__ cbp,
                       bf16_t* __restrict__ outb, int n) {
    int wid = (blockIdx.x * 256 + threadIdx.x) >> 6;
    int lane = threadIdx.x & 63;
    if (wid >= n) return;
    int g = lane >> 4;          // edge sub-group 0..3
    int li = lane & 15;         // feature lane: feats [li*16, li*16+16)
    int loff = li * 16;

    uint4 ur = *(const uint4*)(XR + (size_t)wid * 256 + loff);
    floatx2 xr[8];
    xr[0] = cvtf8<false>(ur.x); xr[1] = cvtf8<true>(ur.x);
    xr[2] = cvtf8<false>(ur.y); xr[3] = cvtf8<true>(ur.y);
    xr[4] = cvtf8<false>(ur.z); xr[5] = cvtf8<true>(ur.z);
    xr[6] = cvtf8<false>(ur.w); xr[7] = cvtf8<true>(ur.w);

    floatx2 wv[8], av6[8];
    const float C6 = 0.6f * 1.44269504f;   // 0.6 * log2(e)
#pragma unroll
    for (int q = 0; q < 4; ++q) {
        float4 wq = ((const float4*)wep)[4 * li + q];
        float4 aq = ((const float4*)attp)[4 * li + q];
        wv[2 * q]     = (floatx2){wq.x, wq.y};
        wv[2 * q + 1] = (floatx2){wq.z, wq.w};
        av6[2 * q]     = (floatx2){aq.x * C6, aq.y * C6};
        av6[2 * q + 1] = (floatx2){aq.z * C6, aq.w * C6};
    }

    int p0 = off[wid], p1 = off[wid + 1];
    float s = 0.f;
    floatx2 a[8];
#pragma unroll
    for (int q = 0; q < 8; ++q) a[q] = (floatx2){0.f, 0.f};

    for (int base = p0; base < p1; base += 64) {
        int rem = p1 - base;
        int cnt = (rem < 64) ? rem : 64;                 // edges in this chunk
        int gp = base + lane; if (gp > p1 - 1) gp = p1 - 1;
        int2 ed = csr[gp];                               // lane l holds edge base+l

        // fetch(j): broadcast src/eav for edge (j+g) from the preloaded regs,
        // then issue the XL gather.  Clamped -> always safe to issue.
        auto fetch = [&](int j, uint4& u, float& ev) {
            int sl = j + g; if (sl >= cnt) sl = cnt - 1;
            int sx = __shfl(ed.x, sl);
            ev = __int_as_float(__shfl(ed.y, sl));
            u = *(const uint4*)(XL + (unsigned)sx * 256u + (unsigned)loff);
        };

        uint4 u0, u1, u2; float e0, e1, e2;
        fetch(0, u0, e0);
        fetch(4, u1, e1);
        fetch(8, u2, e2);

#pragma unroll 3
        for (int j = 0; j < cnt; j += 4) {
            uint4 un; float en;
            fetch(j + 12, un, en);                       // prefetch depth 3
            floatx2 x[8];
            x[0] = cvtf8<false>(u0.x); x[1] = cvtf8<true>(u0.x);
            x[2] = cvtf8<false>(u0.y); x[3] = cvtf8<true>(u0.y);
            x[4] = cvtf8<false>(u0.z); x[5] = cvtf8<true>(u0.z);
            x[6] = cvtf8<false>(u0.w); x[7] = cvtf8<true>(u0.w);
            floatx2 d6, db;
            {
                floatx2 t = x[0] + xr[0] + e0 * wv[0];
                d6 = av6[0] * t;
                db.x = av6[0].x * fabsf(t.x);
                db.y = av6[0].y * fabsf(t.y);
            }
#pragma unroll
            for (int q = 1; q < 8; ++q) {
                floatx2 t = x[q] + xr[q] + e0 * wv[q];
                d6 += av6[q] * t;
                db.x = fmaf(av6[q].x, fabsf(t.x), db.x);
                db.y = fmaf(av6[q].y, fabsf(t.y), db.y);
            }
            // alpha (log2 domain) = sum av6*t + (0.4/0.6)*sum av6*|t|
            float al = fmaf(0.66666667f, db.x + db.y, d6.x + d6.y);
            al = dpp_add<0xB1>(al);                      // xor1 (quad_perm)
            al = dpp_add<0x4E>(al);                      // xor2 -> head sum
            float wg = (j + g < cnt) ? exp2f(al) : 0.0f;
            s += wg;
#pragma unroll
            for (int q = 0; q < 8; ++q) a[q] += wg * x[q];
            u0 = u1; e0 = e1; u1 = u2; e1 = e2; u2 = un; e2 = en;
        }
    }

    // combine the 4 edge groups (lanes xor 16, then xor 32)
    s += __shfl_xor(s, 16);
    s += __shfl_xor(s, 32);
#pragma unroll
    for (int q = 0; q < 8; ++q) {
        a[q].x += __shfl_xor(a[q].x, 16); a[q].y += __shfl_xor(a[q].y, 16);
        a[q].x += __shfl_xor(a[q].x, 32); a[q].y += __shfl_xor(a[q].y, 32);
    }
    if (g == 0) {
        float inv = 1.0f / s;
        float cb[16];
#pragma unroll
        for (int q = 0; q < 4; ++q) {
            float4 bq = ((const float4*)cbp)[4 * li + q];
            cb[4 * q] = bq.x; cb[4 * q + 1] = bq.y;
            cb[4 * q + 2] = bq.z; cb[4 * q + 3] = bq.w;
        }
        bf16x8 o0, o1;
#pragma unroll
        for (int q = 0; q < 4; ++q) {
            o0[2 * q]     = (bf16_t)fmaxf(fmaf(a[q].x, inv, cb[2 * q]), 0.f);
            o0[2 * q + 1] = (bf16_t)fmaxf(fmaf(a[q].y, inv, cb[2 * q + 1]), 0.f);
            o1[2 * q]     = (bf16_t)fmaxf(fmaf(a[q + 4].x, inv, cb[8 + 2 * q]), 0.f);
            o1[2 * q + 1] = (bf16_t)fmaxf(fmaf(a[q + 4].y, inv, cb[8 + 2 * q + 1]), 0.f);
        }
        *(bf16x8*)&outb[(size_t)wid * 256 + loff] = o0;
        *(bf16x8*)&outb[(size_t)wid * 256 + loff + 8] = o1;
    }
}

// K9: global mean pool on bf16 input (sigma2 order preserved in gsum).
__global__ void k_pool(const bf16_t* __restrict__ h, const int* __restrict__ batch,
                       float* __restrict__ gsum, float* __restrict__ gcnt, int n) {
    int j = threadIdx.x;
    int start = blockIdx.x * 32;
    if (start >= n) return;
    int end = start + 32; if (end > n) end = n;
    int cur = batch[start];
    float acc = 0.0f, cnt = 0.0f;
    for (int i = start; i < end; ++i) {
        int g = batch[i];
        if (g != cur) {
            atomicAdd(&gsum[cur * 256 + j], acc);
            if (j == 0) atomicAdd(&gcnt[cur], cnt);
            acc = 0.0f; cnt = 0.0f; cur = g;
        }
        acc += (float)h[(size_t)i * 256 + j];
        cnt += 1.0f;
    }
    atomicAdd(&gsum[cur * 256 + j], acc);
    if (j == 0) atomicAdd(&gcnt[cur], cnt);
}

// K10: post MLP.  gsum is in sigma2 order -> un-permute when loading gv.
__global__ void k_mlp(const float* __restrict__ gsum, const float* __restrict__ gcnt,
                      const float* __restrict__ p1w, const float* __restrict__ p1b,
                      const float* __restrict__ lng, const float* __restrict__ lnb,
                      const float* __restrict__ p2w, const float* __restrict__ p2b,
                      float* __restrict__ out) {
    int g = blockIdx.x;
    int t = threadIdx.x; // 128
    __shared__ float gv[256];
    __shared__ float z[128];
    __shared__ float red[128];
    float invc = 1.0f / fmaxf(gcnt[g], 1.0f);
    gv[sigma2(t)]       = gsum[g * 256 + t] * invc;
    gv[sigma2(t + 128)] = gsum[g * 256 + 128 + t] * invc;
    __syncthreads();
    float z1 = p1b[t];
    for (int k = 0; k < 256; ++k) z1 = fmaf(gv[k], p1w[k * 128 + t], z1);
    red[t] = z1;
    __syncthreads();
    for (int d = 64; d > 0; d >>= 1) { if (t < d) red[t] += red[t + d]; __syncthreads(); }
    float mu = red[0] * (1.0f / 128.0f);
    __syncthreads();
    float dz = z1 - mu;
    red[t] = dz * dz;
    __syncthreads();
    for (int d = 64; d > 0; d >>= 1) { if (t < d) red[t] += red[t + d]; __syncthreads(); }
    float var = red[0] * (1.0f / 128.0f);
    float zn = dz * rsqrtf(var + 1e-5f) * lng[t] + lnb[t];
    z[t] = fmaxf(zn, 0.0f);
    __syncthreads();
    if (t < 64) {
        float o = p2b[t];
        for (int k = 0; k < 128; ++k) o = fmaf(z[k], p2w[k * 64 + t], o);
        out[g * 64 + t] = fmaxf(o, 0.0f);
    }
}

extern "C" void kernel_launch(void* const* d_in, const int* in_sizes, int n_in,
                              void* d_out, int out_size, void* d_ws, size_t ws_size,
                              hipStream_t stream) {
    const float* x      = (const float*)d_in[0];
    const int*   ei     = (const int*)d_in[1];
    const float* ea     = (const float*)d_in[2];
    const int*   batch  = (const int*)d_in[3];
    const float* enc_w  = (const float*)d_in[4];
    const float* enc_b  = (const float*)d_in[5];
    const float* g1_wl  = (const float*)d_in[6];
    const float* g1_bl  = (const float*)d_in[7];
    const float* g1_wr  = (const float*)d_in[8];
    const float* g1_br  = (const float*)d_in[9];
    const float* g1_we  = (const float*)d_in[10];
    const float* g1_att = (const float*)d_in[11];
    const float* g1_bias= (const float*)d_in[12];
    const float* g2_wl  = (const float*)d_in[13];
    const float* g2_bl  = (const float*)d_in[14];
    const float* g2_wr  = (const float*)d_in[15];
    const float* g2_br  = (const float*)d_in[16];
    const float* g2_we  = (const float*)d_in[17];
    const float* g2_att = (const float*)d_in[18];
    const float* g2_bias= (const float*)d_in[19];
    const float* p1_w   = (const float*)d_in[20];
    const float* p1_b   = (const float*)d_in[21];
    const float* ln_g   = (const float*)d_in[22];
    const float* ln_b   = (const float*)d_in[23];
    const float* p2_w   = (const float*)d_in[24];
    const float* p2_b   = (const float*)d_in[25];
    float* out = (float*)d_out;

    const int N  = in_sizes[3];
    const int E  = in_sizes[1] / 2;
    const int EE = E + N;
    const int NB = CDIV(N, 256);

    // workspace carve
    u8*     XL  = (u8*)d_ws;                   // [N,256] fp8 (sigma2)
    u8*     XR  = XL + (size_t)N * 256;        // [N,256] fp8 (sigma2)
    bf16_t* Hb  = (bf16_t*)(XR + (size_t)N * 256); // [N,256] bf16 (conv out)
    bf16_t* Wt  = Hb + (size_t)N * 256;        // [512,256] bf16
    int2*  csr  = (int2*)(Wt + 512 * 256);     // [EE] packed {src, ea}
    float* gsum  = (float*)(csr + EE);         // [32*256] -- zeroed region
    float* gcnt  = gsum + 32 * 256;            // [32]
    int*   deg   = (int*)(gcnt + 32);          // [N]
    int*   cursor= deg + N;                    // [N]  -- zeroed region end
    float* bias2 = (float*)(cursor + N);       // [512]
    float* wep   = bias2 + 512;                // [256]
    float* attp  = wep + 256;                  // [256]
    float* cbp   = attp + 256;                 // [256]
    int*   part  = (int*)(cbp + 256);          // [256]
    int*   off   = part + 256;                 // [N+1]

    (void)hipMemsetAsync(gsum, 0, (size_t)(2 * N + 32 * 256 + 32) * sizeof(float), stream);

    k_deg<<<CDIV(E, 256), 256, 0, stream>>>(ei, deg, E);
    k_scanA<<<NB, 256, 0, stream>>>(deg, part, N);
    k_scanB<<<1, 256, 0, stream>>>(part, NB);
    k_scanC<<<NB, 256, 0, stream>>>(deg, part, off, N);
    k_fill<<<CDIV(E, 256), 256, 0, stream>>>(ei, ea, off, cursor, csr, E);
    k_selfloop<<<NB, 256, 0, stream>>>(off, csr, N);

    dim3 ggrid(CDIV(N, 128), 2);

    // ---- GAT layer 1 (encoder fused into GEMM A-staging, K=64) ----
    k_wcast2<<<CDIV(512 * 64, 256), 256, 0, stream>>>(g1_wl, g1_wr, g1_bl, g1_br, Wt, bias2,
                                                      64, 6, 0, g1_we, g1_att, g1_bias,
                                                      wep, attp, cbp);
    k_gemm1_fused<<<ggrid, 256, 0, stream>>>(x, enc_w, enc_b, Wt, bias2, XL, XR, N);
    k_conv<<<CDIV(N, 4), 256, 0, stream>>>(XL, XR, wep, attp, csr, off, cbp, Hb, N);

    // ---- GAT layer 2 (K sigma2-permuted to match Hb layout) ----
    k_wcast2<<<CDIV(512 * 256, 256), 256, 0, stream>>>(g2_wl, g2_wr, g2_bl, g2_br, Wt, bias2,
                                                       256, 8, 1, g2_we, g2_att, g2_bias,
                                                       wep, attp, cbp);
    k_gemm2<<<ggrid, 256, 0, stream>>>(Hb, Wt, bias2, XL, XR, N);
    k_conv<<<CDIV(N, 4), 256, 0, stream>>>(XL, XR, wep, attp, csr, off, cbp, Hb, N);

    // ---- pool + MLP ----
    k_pool<<<CDIV(N, 32), 256, 0, stream>>>(Hb, batch, gsum, gcnt, N);
    k_mlp<<<32, 128, 0, stream>>>(gsum, gcnt, p1_w, p1_b, ln_g, ln_b, p2_w, p2_b, out);
}

// Round 3
// 444.531 us; speedup vs baseline: 1.0350x; 1.0350x over previous
//
#include <hip/hip_runtime.h>

#define CDIV(a,b) (((a)+(b)-1)/(b))

typedef __bf16 bf16_t;
typedef unsigned char u8;
typedef bf16_t bf16x8 __attribute__((ext_vector_type(8)));
typedef float floatx4 __attribute__((ext_vector_type(4)));
typedef float floatx2 __attribute__((ext_vector_type(2)));

// sigma2: storage position p -> original feature index (within 256).
__device__ __forceinline__ int sigma2(int p) {
    int tile = p >> 7, hh = (p >> 6) & 1, m = (p >> 2) & 15, c = p & 3;
    return tile * 128 + (hh * 4 + c) * 16 + m;
}

// pack 4 fp32 -> 4 OCP e4m3 bytes
__device__ __forceinline__ unsigned pack4_fp8(float a, float b, float c, float d) {
    int v = __builtin_amdgcn_cvt_pk_fp8_f32(a, b, 0, false);   // bytes [1:0]
    v = __builtin_amdgcn_cvt_pk_fp8_f32(c, d, v, true);        // bytes [3:2]
    return (unsigned)v;
}

template<bool HI>
__device__ __forceinline__ floatx2 cvtf8(unsigned v) {
    return __builtin_amdgcn_cvt_pk_f32_fp8(v, HI);   // HI is constexpr
}

// DPP butterfly add: x + lane-permuted(x).  CTRL: 0xB1 = quad_perm xor1,
// 0x4E = quad_perm xor2, 0x141 = row_half_mirror (== xor4 once values are
// 4-lane-group uniform).  Pure VALU — no lgkmcnt wait like ds_swizzle.
template<int CTRL>
__device__ __forceinline__ float dpp_add(float x) {
    int v = __builtin_amdgcn_update_dpp(0, __float_as_int(x), CTRL, 0xf, 0xf, true);
    return x + __int_as_float(v);
}

// ---------------------------------------------------------------------------
// K1: per-original-edge degree count (single atomic; edge-attr sum for the
// self-loop fill moved to k_selfloop, which is atomic-free).
__global__ void k_deg(const int* __restrict__ ei, int* __restrict__ deg, int E) {
    int e = blockIdx.x * 256 + threadIdx.x;
    if (e >= E) return;
    atomicAdd(&deg[ei[E + e]], 1);
}

// K3: parallel exclusive scan of (deg[i]+1) -> off[0..n], 3 phases.
__global__ void k_scanA(const int* __restrict__ deg, int* __restrict__ part, int n) {
    __shared__ int sh[256];
    int t = threadIdx.x;
    int i = blockIdx.x * 256 + t;
    int v = (i < n) ? deg[i] + 1 : 0;
    sh[t] = v;
    __syncthreads();
    for (int d = 128; d > 0; d >>= 1) { if (t < d) sh[t] += sh[t + d]; __syncthreads(); }
    if (t == 0) part[blockIdx.x] = sh[0];
}
__global__ void k_scanB(int* __restrict__ part, int nb) {
    __shared__ int sh[256];
    int t = threadIdx.x;
    int v = (t < nb) ? part[t] : 0;
    sh[t] = v;
    __syncthreads();
    for (int d = 1; d < 256; d <<= 1) {
        int u = (t >= d) ? sh[t - d] : 0;
        __syncthreads();
        sh[t] += u;
        __syncthreads();
    }
    if (t < nb) part[t] = sh[t] - v;   // exclusive
}
__global__ void k_scanC(const int* __restrict__ deg, const int* __restrict__ part,
                        int* __restrict__ off, int n) {
    __shared__ int sh[256];
    int t = threadIdx.x;
    int i = blockIdx.x * 256 + t;
    int v = (i < n) ? deg[i] + 1 : 0;
    sh[t] = v;
    __syncthreads();
    for (int d = 1; d < 256; d <<= 1) {
        int u = (t >= d) ? sh[t - d] : 0;
        __syncthreads();
        sh[t] += u;
        __syncthreads();
    }
    int excl = part[blockIdx.x] + sh[t] - v;
    if (i < n) off[i] = excl;
    if (i == n - 1) off[n] = excl + v;
}

// K4: CSR fill of ORIGINAL edges only; originals occupy [off[d], off[d+1]-1),
// the last slot of each segment is reserved for the self-loop (k_selfloop).
__global__ void k_fill(const int* __restrict__ ei, const float* __restrict__ ea,
                       const int* __restrict__ off, int* __restrict__ cursor,
                       int2* __restrict__ csr, int E) {
    int e = blockIdx.x * 256 + threadIdx.x;
    if (e >= E) return;
    int s = ei[e], d = ei[E + e];
    int pos = off[d] + atomicAdd(&cursor[d], 1);
    csr[pos] = make_int2(s, __float_as_int(ea[e]));
}

// K4b: per-node self-loop entry (atomic-free).  Sums the segment's original
// edge attrs -> loop_attr = sum / max(deg,1); writes csr[off[i+1]-1].
__global__ void k_selfloop(const int* __restrict__ off, int2* __restrict__ csr, int n) {
    int i = blockIdx.x * 256 + threadIdx.x;
    if (i >= n) return;
    int p0 = off[i], p1 = off[i + 1] - 1;   // originals in [p0, p1)
    float s = 0.0f;
    for (int p = p0; p < p1; ++p) s += __int_as_float(csr[p].y);
    float la = s / fmaxf((float)(p1 - p0), 1.0f);
    csr[p1] = make_int2(i, __float_as_int(la));
}

// K5c: combined weight transpose+cast Wl,Wr[K,256] fp32 -> Wt[512,K] bf16.
__global__ void k_wcast2(const float* __restrict__ Wl, const float* __restrict__ Wr,
                         const float* __restrict__ bl, const float* __restrict__ br,
                         bf16_t* __restrict__ Wt, float* __restrict__ bias2,
                         int K, int kshift, int permK,
                         const float* __restrict__ we, const float* __restrict__ att,
                         const float* __restrict__ cb,
                         float* __restrict__ wep, float* __restrict__ attp,
                         float* __restrict__ cbp) {
    int idx = blockIdx.x * 256 + threadIdx.x;
    if (idx < 512) bias2[idx] = (idx < 256) ? bl[idx] : br[idx - 256];
    if (idx < 256) {
        int sg = sigma2(idx);
        wep[idx] = we[sg]; attp[idx] = att[sg]; cbp[idx] = cb[sg];
    }
    if (idx >= 512 * K) return;
    int nn = idx >> kshift, k = idx & (K - 1);
    int ks = permK ? sigma2(k) : k;
    float v = (nn < 256) ? Wl[ks * 256 + nn] : Wr[ks * 256 + (nn - 256)];
    Wt[idx] = (bf16_t)v;
}

// K6a: layer-1 GEMM with fused encoder.  grid.y=2 splits the 4 col-tiles.
__global__ __launch_bounds__(256) void k_gemm1_fused(
        const float* __restrict__ x, const float* __restrict__ encw,
        const float* __restrict__ encb, const bf16_t* __restrict__ Wt,
        const float* __restrict__ bias2, u8* __restrict__ XL,
        u8* __restrict__ XR, int nrows) {
    __shared__ bf16_t As[128 * 32];
    __shared__ bf16_t Bs[128 * 32];
    int tid = threadIdx.x;
    int w = tid >> 6, lane = tid & 63;
    int quad = lane >> 4, m = lane & 15;
    int row0 = blockIdx.x * 128;
    int ct0 = blockIdx.y * 2;
    bf16x8 afr[2][2];
    floatx4 acc[2][8];

    for (int ctile = ct0; ctile < ct0 + 2; ++ctile) {
        int n0 = ctile * 128;
#pragma unroll
        for (int rt = 0; rt < 2; ++rt)
#pragma unroll
            for (int ct = 0; ct < 8; ++ct)
                acc[rt][ct] = (floatx4){0.f, 0.f, 0.f, 0.f};
        for (int k0c = 0; k0c < 2; ++k0c) {
            __syncthreads();
            if (ctile == ct0) {
#pragma unroll
                for (int i = 0; i < 2; ++i) {  // stage A: fused encoder
                    int c = tid + i * 256;
                    int r = c >> 2, kc = c & 3;
                    int sw = (kc + (r >> 1)) & 3;
                    int gr = row0 + r; if (gr >= nrows) gr = nrows - 1;
                    float4 xv = ((const float4*)x)[gr];
                    bf16x8 v;
#pragma unroll
                    for (int kk = 0; kk < 8; ++kk) {
                        int k = k0c * 32 + kc * 8 + kk;
                        float s = encb[k];
                        s = fmaf(xv.x, encw[k], s);
                        s = fmaf(xv.y, encw[64 + k], s);
                        s = fmaf(xv.z, encw[128 + k], s);
                        s = fmaf(xv.w, encw[192 + k], s);
                        v[kk] = (bf16_t)fmaxf(s, 0.0f);
                    }
                    *(bf16x8*)&As[r * 32 + sw * 8] = v;
                }
            }
#pragma unroll
            for (int i = 0; i < 2; ++i) {      // stage B for this col-tile
                int c = tid + i * 256;
                int r = c >> 2, kc = c & 3;
                int sw = (kc + (r >> 1)) & 3;
                bf16x8 v = *(const bf16x8*)&Wt[(size_t)(n0 + r) * 64 + k0c * 32 + kc * 8];
                *(bf16x8*)&Bs[r * 32 + sw * 8] = v;
            }
            __syncthreads();
            if (ctile == ct0) {
#pragma unroll
                for (int rt = 0; rt < 2; ++rt) {
                    int ar = w * 32 + rt * 16 + m;
                    afr[k0c][rt] = *(bf16x8*)&As[ar * 32 + (((quad + (ar >> 1)) & 3) * 8)];
                }
            }
            bf16x8 bfr[8];
#pragma unroll
            for (int ct = 0; ct < 8; ++ct) {
                int br = ct * 16 + m;
                bfr[ct] = *(bf16x8*)&Bs[br * 32 + (((quad + (br >> 1)) & 3) * 8)];
            }
#pragma unroll
            for (int ct = 0; ct < 8; ++ct) {
                acc[0][ct] = __builtin_amdgcn_mfma_f32_16x16x32_bf16(afr[k0c][0], bfr[ct], acc[0][ct], 0, 0, 0);
                acc[1][ct] = __builtin_amdgcn_mfma_f32_16x16x32_bf16(afr[k0c][1], bfr[ct], acc[1][ct], 0, 0, 0);
            }
        }
        int tile = ctile & 1;
        u8* dst = (ctile < 2) ? XL : XR;
        float bv[8];
#pragma unroll
        for (int ct = 0; ct < 8; ++ct) bv[ct] = bias2[n0 + ct * 16 + m];
#pragma unroll
        for (int rt = 0; rt < 2; ++rt) {
#pragma unroll
            for (int i = 0; i < 4; ++i) {
                int row = row0 + w * 32 + rt * 16 + quad * 4 + i;
                if (row < nrows) {
                    unsigned w0 = pack4_fp8(acc[rt][0][i] + bv[0], acc[rt][1][i] + bv[1],
                                            acc[rt][2][i] + bv[2], acc[rt][3][i] + bv[3]);
                    unsigned w1 = pack4_fp8(acc[rt][4][i] + bv[4], acc[rt][5][i] + bv[5],
                                            acc[rt][6][i] + bv[6], acc[rt][7][i] + bv[7]);
                    *(unsigned*)&dst[(size_t)row * 256 + tile * 128 + m * 4] = w0;
                    *(unsigned*)&dst[(size_t)row * 256 + tile * 128 + 64 + m * 4] = w1;
                }
            }
        }
    }
}

// K6b: layer-2 GEMM (K=256), grid.y=2 col-tile split; A staged once/block.
__global__ __launch_bounds__(256) void k_gemm2(
        const bf16_t* __restrict__ Hb, const bf16_t* __restrict__ Wt,
        const float* __restrict__ bias2, u8* __restrict__ XL,
        u8* __restrict__ XR, int nrows) {
    const int K = 256;
    __shared__ bf16_t As[128 * 32];
    __shared__ bf16_t Bs[128 * 32];
    int tid = threadIdx.x;
    int w = tid >> 6, lane = tid & 63;
    int quad = lane >> 4, m = lane & 15;
    int row0 = blockIdx.x * 128;
    int ct0 = blockIdx.y * 2;
    bf16x8 afr[8][2];
    floatx4 acc[2][8];

    for (int ctile = ct0; ctile < ct0 + 2; ++ctile) {
        int n0 = ctile * 128;
#pragma unroll
        for (int rt = 0; rt < 2; ++rt)
#pragma unroll
            for (int ct = 0; ct < 8; ++ct)
                acc[rt][ct] = (floatx4){0.f, 0.f, 0.f, 0.f};
        for (int k0c = 0; k0c < 8; ++k0c) {
            __syncthreads();
            if (ctile == ct0) {
#pragma unroll
                for (int i = 0; i < 2; ++i) {
                    int c = tid + i * 256;
                    int r = c >> 2, kc = c & 3;
                    int sw = (kc + (r >> 1)) & 3;
                    int gr = row0 + r; if (gr >= nrows) gr = nrows - 1;
                    bf16x8 v = *(const bf16x8*)&Hb[(size_t)gr * K + k0c * 32 + kc * 8];
                    *(bf16x8*)&As[r * 32 + sw * 8] = v;
                }
            }
#pragma unroll
            for (int i = 0; i < 2; ++i) {
                int c = tid + i * 256;
                int r = c >> 2, kc = c & 3;
                int sw = (kc + (r >> 1)) & 3;
                bf16x8 v = *(const bf16x8*)&Wt[(size_t)(n0 + r) * K + k0c * 32 + kc * 8];
                *(bf16x8*)&Bs[r * 32 + sw * 8] = v;
            }
            __syncthreads();
            if (ctile == ct0) {
#pragma unroll
                for (int rt = 0; rt < 2; ++rt) {
                    int ar = w * 32 + rt * 16 + m;
                    afr[k0c][rt] = *(bf16x8*)&As[ar * 32 + (((quad + (ar >> 1)) & 3) * 8)];
                }
            }
            bf16x8 bfr[8];
#pragma unroll
            for (int ct = 0; ct < 8; ++ct) {
                int br = ct * 16 + m;
                bfr[ct] = *(bf16x8*)&Bs[br * 32 + (((quad + (br >> 1)) & 3) * 8)];
            }
#pragma unroll
            for (int ct = 0; ct < 8; ++ct) {
                acc[0][ct] = __builtin_amdgcn_mfma_f32_16x16x32_bf16(afr[k0c][0], bfr[ct], acc[0][ct], 0, 0, 0);
                acc[1][ct] = __builtin_amdgcn_mfma_f32_16x16x32_bf16(afr[k0c][1], bfr[ct], acc[1][ct], 0, 0, 0);
            }
        }
        int tile = ctile & 1;
        u8* dst = (ctile < 2) ? XL : XR;
        float bv[8];
#pragma unroll
        for (int ct = 0; ct < 8; ++ct) bv[ct] = bias2[n0 + ct * 16 + m];
#pragma unroll
        for (int rt = 0; rt < 2; ++rt) {
#pragma unroll
            for (int i = 0; i < 4; ++i) {
                int row = row0 + w * 32 + rt * 16 + quad * 4 + i;
                if (row < nrows) {
                    unsigned w0 = pack4_fp8(acc[rt][0][i] + bv[0], acc[rt][1][i] + bv[1],
                                            acc[rt][2][i] + bv[2], acc[rt][3][i] + bv[3]);
                    unsigned w1 = pack4_fp8(acc[rt][4][i] + bv[4], acc[rt][5][i] + bv[5],
                                            acc[rt][6][i] + bv[6], acc[rt][7][i] + bv[7]);
                    *(unsigned*)&dst[(size_t)row * 256 + tile * 128 + m * 4] = w0;
                    *(unsigned*)&dst[(size_t)row * 256 + tile * 128 + 64 + m * 4] = w1;
                }
            }
        }
    }
}

// K7: fused GATv2 conv, fp8 XL/XR (256B/edge), sigma2 layout.
// R3: TWO waves per node (4 waves/block = 2 nodes).  Wave hs ∈ {0,1} owns
// edges at positions ≡ {2hs, 2hs+1} (mod 4) — interleaved at 2-edge
// granularity so both waves get work at deg≈17.  Each wave = R1 structure:
// two 32-lane halves on different edges, lane covers 8 features; per-chunk
// wave-wide csr preload + __shfl broadcast (no serial load chain); XL
// gathers software-pipelined depth 3; 8-lane head reduce via DPP.
// Partials merged via LDS (9 floats/lane, stride 9 = conflict-free).
// R2 POST-MORTEM: 16-lane/edge × 4 edges regressed (VGPR 64, occupancy
// 36%, VALUBusy 56%) — wider per-edge footprint loses more occupancy than
// it saves in amortization.  Keep 32-lane/edge, VGPR ~40.
// Plain (cached) csr loads + Hb stores: non-temporal hints REGRESS (R15).
// NOTE: pool fusion reverted — R9: same-graph atomics serialize.
__global__ void k_conv(
                       const u8* __restrict__ XL, const u8* __restrict__ XR,
                       const float* __restrict__ wep, const float* __restrict__ attp,
                       const int2* __restrict__ csr,
                       const int* __restrict__ off, const float* __restrict__ cbp,
                       bf16_t* __restrict__ outb, int n) {
    int tid = threadIdx.x;
    int w = tid >> 6;               // wave in block 0..3
    int nib = w >> 1;               // node-in-block 0..1
    int hs = w & 1;                 // which half of the edge list
    int node = blockIdx.x * 2 + nib;
    int lane = tid & 63;
    int half = lane >> 5, l = lane & 31;
    int loff = l * 8;
    bool active = node < n;
    int nc = active ? node : n - 1;

    uint2 ur = *(const uint2*)(XR + (size_t)nc * 256 + loff);
    floatx2 xr01 = cvtf8<false>(ur.x);
    floatx2 xr23 = cvtf8<true>(ur.x);
    floatx2 xr45 = cvtf8<false>(ur.y);
    floatx2 xr67 = cvtf8<true>(ur.y);
    float4 wa = ((const float4*)wep)[2 * l], wb = ((const float4*)wep)[2 * l + 1];
    float4 aa = ((const float4*)attp)[2 * l], ab = ((const float4*)attp)[2 * l + 1];
    floatx2 wv01 = {wa.x, wa.y}, wv23 = {wa.z, wa.w};
    floatx2 wv45 = {wb.x, wb.y}, wv67 = {wb.z, wb.w};
    const float LOG2E = 1.44269504f;
    floatx2 av01 = {aa.x * LOG2E, aa.y * LOG2E}, av23 = {aa.z * LOG2E, aa.w * LOG2E};
    floatx2 av45 = {ab.x * LOG2E, ab.y * LOG2E}, av67 = {ab.z * LOG2E, ab.w * LOG2E};
    int p0 = off[nc], p1 = off[nc + 1];
    float s = 0.f;
    floatx2 a01 = {0.f, 0.f}, a23 = {0.f, 0.f}, a45 = {0.f, 0.f}, a67 = {0.f, 0.f};

    if (active) {
        // chunk of 128 edge slots; this wave's lanes map to the 64 slots
        // at positions 2hs..  (pairs interleaved mod 4), monotone in lane.
        for (int cbase = p0; cbase < p1; cbase += 128) {
            int gp = cbase + 2 * hs + ((lane >> 1) << 2) + (lane & 1);
            bool vld = gp < p1;
            int gpc = vld ? gp : p1 - 1;
            int2 ed = csr[gpc];                       // lane i holds edge e_i
            int cnt = (int)__popcll(__ballot(vld));   // valid lanes are a prefix

            if (cnt > 0) {
                auto fetch = [&](int j, uint2& u, float& ev) {
                    int sl = j + half; if (sl >= cnt) sl = cnt - 1;
                    int sx = __shfl(ed.x, sl);
                    ev = __int_as_float(__shfl(ed.y, sl));
                    u = *(const uint2*)(XL + (unsigned)(sx * 256 + loff));
                };

                uint2 u0, u1, u2; float e0, e1, e2;
                fetch(0, u0, e0);
                fetch(2, u1, e1);
                fetch(4, u2, e2);

#pragma unroll 3
                for (int j = 0; j < cnt; j += 2) {
                    uint2 un; float en;
                    fetch(j + 6, un, en);             // prefetch depth 3
                    floatx2 x01 = cvtf8<false>(u0.x);
                    floatx2 x23 = cvtf8<true>(u0.x);
                    floatx2 x45 = cvtf8<false>(u0.y);
                    floatx2 x67 = cvtf8<true>(u0.y);
                    floatx2 t01 = x01 + xr01 + e0 * wv01;
                    floatx2 t23 = x23 + xr23 + e0 * wv23;
                    floatx2 t45 = x45 + xr45 + e0 * wv45;
                    floatx2 t67 = x67 + xr67 + e0 * wv67;
                    t01 = __builtin_elementwise_max(t01, 0.2f * t01);
                    t23 = __builtin_elementwise_max(t23, 0.2f * t23);
                    t45 = __builtin_elementwise_max(t45, 0.2f * t45);
                    t67 = __builtin_elementwise_max(t67, 0.2f * t67);
                    floatx2 d = t01 * av01 + t23 * av23 + t45 * av45 + t67 * av67;
                    float al = d.x + d.y;
                    al = dpp_add<0xB1>(al);           // xor1 (quad_perm)
                    al = dpp_add<0x4E>(al);           // xor2 (quad_perm)
                    al = dpp_add<0x141>(al);          // xor4 (row_half_mirror)
                    float wg = (j + half < cnt) ? exp2f(al) : 0.0f;  // att pre-scaled 1/ln2
                    s += wg;
                    a01 += wg * x01; a23 += wg * x23; a45 += wg * x45; a67 += wg * x67;
                    u0 = u1; e0 = e1; u1 = u2; e1 = e2; u2 = un; e2 = en;
                }
            }
        }
    }

    // combine the two 32-lane halves within this wave
    s += __shfl_xor(s, 32);
    a01.x += __shfl_xor(a01.x, 32); a01.y += __shfl_xor(a01.y, 32);
    a23.x += __shfl_xor(a23.x, 32); a23.y += __shfl_xor(a23.y, 32);
    a45.x += __shfl_xor(a45.x, 32); a45.y += __shfl_xor(a45.y, 32);
    a67.x += __shfl_xor(a67.x, 32); a67.y += __shfl_xor(a67.y, 32);

    // merge the two waves of this node via LDS (stride 9 -> conflict-free)
    __shared__ float shm[2][32][9];
    if (active && hs == 1 && half == 0) {
        float* d = shm[nib][l];
        d[0] = s;
        d[1] = a01.x; d[2] = a01.y; d[3] = a23.x; d[4] = a23.y;
        d[5] = a45.x; d[6] = a45.y; d[7] = a67.x; d[8] = a67.y;
    }
    __syncthreads();
    if (active && hs == 0 && half == 0) {
        const float* m = shm[nib][l];
        s += m[0];
        a01.x += m[1]; a01.y += m[2]; a23.x += m[3]; a23.y += m[4];
        a45.x += m[5]; a45.y += m[6]; a67.x += m[7]; a67.y += m[8];
        float inv = 1.0f / s;
        float4 ba = ((const float4*)cbp)[2 * l], bb = ((const float4*)cbp)[2 * l + 1];
        bf16x8 ob;
        ob[0] = (bf16_t)fmaxf(fmaf(a01.x, inv, ba.x), 0.f);
        ob[1] = (bf16_t)fmaxf(fmaf(a01.y, inv, ba.y), 0.f);
        ob[2] = (bf16_t)fmaxf(fmaf(a23.x, inv, ba.z), 0.f);
        ob[3] = (bf16_t)fmaxf(fmaf(a23.y, inv, ba.w), 0.f);
        ob[4] = (bf16_t)fmaxf(fmaf(a45.x, inv, bb.x), 0.f);
        ob[5] = (bf16_t)fmaxf(fmaf(a45.y, inv, bb.y), 0.f);
        ob[6] = (bf16_t)fmaxf(fmaf(a67.x, inv, bb.z), 0.f);
        ob[7] = (bf16_t)fmaxf(fmaf(a67.y, inv, bb.w), 0.f);
        *(bf16x8*)&outb[(size_t)node * 256 + l * 8] = ob;
    }
}

// K9: global mean pool on bf16 input (sigma2 order preserved in gsum).
__global__ void k_pool(const bf16_t* __restrict__ h, const int* __restrict__ batch,
                       float* __restrict__ gsum, float* __restrict__ gcnt, int n) {
    int j = threadIdx.x;
    int start = blockIdx.x * 32;
    if (start >= n) return;
    int end = start + 32; if (end > n) end = n;
    int cur = batch[start];
    float acc = 0.0f, cnt = 0.0f;
    for (int i = start; i < end; ++i) {
        int g = batch[i];
        if (g != cur) {
            atomicAdd(&gsum[cur * 256 + j], acc);
            if (j == 0) atomicAdd(&gcnt[cur], cnt);
            acc = 0.0f; cnt = 0.0f; cur = g;
        }
        acc += (float)h[(size_t)i * 256 + j];
        cnt += 1.0f;
    }
    atomicAdd(&gsum[cur * 256 + j], acc);
    if (j == 0) atomicAdd(&gcnt[cur], cnt);
}

// K10: post MLP.  gsum is in sigma2 order -> un-permute when loading gv.
__global__ void k_mlp(const float* __restrict__ gsum, const float* __restrict__ gcnt,
                      const float* __restrict__ p1w, const float* __restrict__ p1b,
                      const float* __restrict__ lng, const float* __restrict__ lnb,
                      const float* __restrict__ p2w, const float* __restrict__ p2b,
                      float* __restrict__ out) {
    int g = blockIdx.x;
    int t = threadIdx.x; // 128
    __shared__ float gv[256];
    __shared__ float z[128];
    __shared__ float red[128];
    float invc = 1.0f / fmaxf(gcnt[g], 1.0f);
    gv[sigma2(t)]       = gsum[g * 256 + t] * invc;
    gv[sigma2(t + 128)] = gsum[g * 256 + 128 + t] * invc;
    __syncthreads();
    float z1 = p1b[t];
    for (int k = 0; k < 256; ++k) z1 = fmaf(gv[k], p1w[k * 128 + t], z1);
    red[t] = z1;
    __syncthreads();
    for (int d = 64; d > 0; d >>= 1) { if (t < d) red[t] += red[t + d]; __syncthreads(); }
    float mu = red[0] * (1.0f / 128.0f);
    __syncthreads();
    float dz = z1 - mu;
    red[t] = dz * dz;
    __syncthreads();
    for (int d = 64; d > 0; d >>= 1) { if (t < d) red[t] += red[t + d]; __syncthreads(); }
    float var = red[0] * (1.0f / 128.0f);
    float zn = dz * rsqrtf(var + 1e-5f) * lng[t] + lnb[t];
    z[t] = fmaxf(zn, 0.0f);
    __syncthreads();
    if (t < 64) {
        float o = p2b[t];
        for (int k = 0; k < 128; ++k) o = fmaf(z[k], p2w[k * 64 + t], o);
        out[g * 64 + t] = fmaxf(o, 0.0f);
    }
}

extern "C" void kernel_launch(void* const* d_in, const int* in_sizes, int n_in,
                              void* d_out, int out_size, void* d_ws, size_t ws_size,
                              hipStream_t stream) {
    const float* x      = (const float*)d_in[0];
    const int*   ei     = (const int*)d_in[1];
    const float* ea     = (const float*)d_in[2];
    const int*   batch  = (const int*)d_in[3];
    const float* enc_w  = (const float*)d_in[4];
    const float* enc_b  = (const float*)d_in[5];
    const float* g1_wl  = (const float*)d_in[6];
    const float* g1_bl  = (const float*)d_in[7];
    const float* g1_wr  = (const float*)d_in[8];
    const float* g1_br  = (const float*)d_in[9];
    const float* g1_we  = (const float*)d_in[10];
    const float* g1_att = (const float*)d_in[11];
    const float* g1_bias= (const float*)d_in[12];
    const float* g2_wl  = (const float*)d_in[13];
    const float* g2_bl  = (const float*)d_in[14];
    const float* g2_wr  = (const float*)d_in[15];
    const float* g2_br  = (const float*)d_in[16];
    const float* g2_we  = (const float*)d_in[17];
    const float* g2_att = (const float*)d_in[18];
    const float* g2_bias= (const float*)d_in[19];
    const float* p1_w   = (const float*)d_in[20];
    const float* p1_b   = (const float*)d_in[21];
    const float* ln_g   = (const float*)d_in[22];
    const float* ln_b   = (const float*)d_in[23];
    const float* p2_w   = (const float*)d_in[24];
    const float* p2_b   = (const float*)d_in[25];
    float* out = (float*)d_out;

    const int N  = in_sizes[3];
    const int E  = in_sizes[1] / 2;
    const int EE = E + N;
    const int NB = CDIV(N, 256);

    // workspace carve
    u8*     XL  = (u8*)d_ws;                   // [N,256] fp8 (sigma2)
    u8*     XR  = XL + (size_t)N * 256;        // [N,256] fp8 (sigma2)
    bf16_t* Hb  = (bf16_t*)(XR + (size_t)N * 256); // [N,256] bf16 (conv out)
    bf16_t* Wt  = Hb + (size_t)N * 256;        // [512,256] bf16
    int2*  csr  = (int2*)(Wt + 512 * 256);     // [EE] packed {src, ea}
    float* gsum  = (float*)(csr + EE);         // [32*256] -- zeroed region
    float* gcnt  = gsum + 32 * 256;            // [32]
    int*   deg   = (int*)(gcnt + 32);          // [N]
    int*   cursor= deg + N;                    // [N]  -- zeroed region end
    float* bias2 = (float*)(cursor + N);       // [512]
    float* wep   = bias2 + 512;                // [256]
    float* attp  = wep + 256;                  // [256]
    float* cbp   = attp + 256;                 // [256]
    int*   part  = (int*)(cbp + 256);          // [256]
    int*   off   = part + 256;                 // [N+1]

    (void)hipMemsetAsync(gsum, 0, (size_t)(2 * N + 32 * 256 + 32) * sizeof(float), stream);

    k_deg<<<CDIV(E, 256), 256, 0, stream>>>(ei, deg, E);
    k_scanA<<<NB, 256, 0, stream>>>(deg, part, N);
    k_scanB<<<1, 256, 0, stream>>>(part, NB);
    k_scanC<<<NB, 256, 0, stream>>>(deg, part, off, N);
    k_fill<<<CDIV(E, 256), 256, 0, stream>>>(ei, ea, off, cursor, csr, E);
    k_selfloop<<<NB, 256, 0, stream>>>(off, csr, N);

    dim3 ggrid(CDIV(N, 128), 2);

    // ---- GAT layer 1 (encoder fused into GEMM A-staging, K=64) ----
    k_wcast2<<<CDIV(512 * 64, 256), 256, 0, stream>>>(g1_wl, g1_wr, g1_bl, g1_br, Wt, bias2,
                                                      64, 6, 0, g1_we, g1_att, g1_bias,
                                                      wep, attp, cbp);
    k_gemm1_fused<<<ggrid, 256, 0, stream>>>(x, enc_w, enc_b, Wt, bias2, XL, XR, N);
    k_conv<<<CDIV(N, 2), 256, 0, stream>>>(XL, XR, wep, attp, csr, off, cbp, Hb, N);

    // ---- GAT layer 2 (K sigma2-permuted to match Hb layout) ----
    k_wcast2<<<CDIV(512 * 256, 256), 256, 0, stream>>>(g2_wl, g2_wr, g2_bl, g2_br, Wt, bias2,
                                                       256, 8, 1, g2_we, g2_att, g2_bias,
                                                       wep, attp, cbp);
    k_gemm2<<<ggrid, 256, 0, stream>>>(Hb, Wt, bias2, XL, XR, N);
    k_conv<<<CDIV(N, 2), 256, 0, stream>>>(XL, XR, wep, attp, csr, off, cbp, Hb, N);

    // ---- pool + MLP ----
    k_pool<<<CDIV(N, 32), 256, 0, stream>>>(Hb, batch, gsum, gcnt, N);
    k_mlp<<<32, 128, 0, stream>>>(gsum, gcnt, p1_w, p1_b, ln_g, ln_b, p2_w, p2_b, out);
}